// Round 13
// baseline (1286.093 us; speedup 1.0000x reference)
//
#include <hip/hip_runtime.h>
#include <math.h>

typedef __bf16 bf16x8 __attribute__((ext_vector_type(8)));
typedef float f32x4 __attribute__((ext_vector_type(4)));
typedef float f32x16 __attribute__((ext_vector_type(16)));
typedef short short8 __attribute__((ext_vector_type(8)));
typedef unsigned int uint4v __attribute__((ext_vector_type(4)));

__device__ __forceinline__ float bf2f(unsigned short u) {
  union { unsigned int i; float f; } v; v.i = ((unsigned int)u) << 16; return v.f;
}
__device__ __forceinline__ unsigned short f2bf(float f) {
  union { float fl; unsigned int i; } v; v.fl = f;
  unsigned int x = v.i;
  return (unsigned short)((x + 0x7FFFu + ((x >> 16) & 1u)) >> 16);  // RNE
}
__device__ __forceinline__ unsigned int cvt_pk_bf16(float lo, float hi) {
  unsigned int r;
  asm("v_cvt_pk_bf16_f32 %0, %1, %2" : "=v"(r) : "v"(lo), "v"(hi));
  return r;
}
// async global->LDS, 16B per lane. lds ptr wave-uniform (HW adds lane*16).
__device__ __forceinline__ void gl_lds16(const unsigned short* g, void* l) {
  __builtin_amdgcn_global_load_lds(
      (const __attribute__((address_space(1))) unsigned int*)g,
      (__attribute__((address_space(3))) unsigned int*)l, 16, 0, 0);
}

// ============================================================================
// 256x256 bf16 GEMM, R13: 32x32x16 MFMA (2x FLOP/instr, -17% MFMA time) on
// the R12 minimal-barrier drift schedule. Swizzle upgraded to
// f(row) = ((row&7) ^ ((row>>3)&3)) << 4 so 32-row-span fragment reads
// spread r/r+8/r+16/r+24 across 4 slots (R4's 4-way aliasing mitigated).
// Epilogue uses the R4-verified 32x32 C/D map: col=lane&31,
// row=(r&3)+8*(r>>2)+4*(lane>>5).
//  BATCH=1: z-major XCD-chunked batched mode. SPLIT3: q|k|vT routing.
// Hazard ledger: identical to R12 (2 barriers/tile, pre-MFMA; counted
// vmcnt(4); per-phase lgkmcnt(0) self-drain).
// ============================================================================
template<int BATCH, int SPLIT3, int CF32, int HAS_BIAS>
__global__ __launch_bounds__(512)
void gemm256(const unsigned short* __restrict__ A,
             const unsigned short* __restrict__ B,
             const float* __restrict__ b0, const float* __restrict__ b1,
             const float* __restrict__ b2,
             void* __restrict__ C0, void* __restrict__ C1, void* __restrict__ C2,
             int K, int lda, int ldb, int ldc, int nbn, float alpha,
             long sAo, long sAi, int nAi,
             long sBo, long sBi, int nBi,
             long sCo, long sCi, int nCi)
{
  __shared__ alignas(16) unsigned char LDS[131072];
  const int NT = K >> 6;   // even, >= 2

  int tm, tn;
  long offA = 0, offB = 0, offC = 0;
  if (BATCH) {
    const int nbx = (int)gridDim.x;
    const int nf = nbx * (int)gridDim.z;
    const int f = (int)blockIdx.z * nbx + (int)blockIdx.x;
    const int s = (f & 7) * (nf >> 3) + (f >> 3);
    const int bx = s % nbx;
    const int z = s / nbx;
    tm = (bx / nbn) * 256;
    tn = (bx % nbn) * 256;
    offA = (long)(z / nAi) * sAo + (long)(z % nAi) * sAi;
    offB = (long)(z / nBi) * sBo + (long)(z % nBi) * sBi;
    offC = (long)(z / nCi) * sCo + (long)(z % nCi) * sCi;
  } else {
    const int nwg = (int)gridDim.x;
    const int bid = (int)blockIdx.x;
    const int s = (bid & 7) * (nwg >> 3) + (bid >> 3);
    const int sTile = s >> 4, w = s & 15;
    const int snb = nbn >> 2;
    tm = ((sTile / snb) * 4 + (w >> 2)) * 256;
    tn = ((sTile % snb) * 4 + (w & 3)) * 256;
  }

  const int tid = (int)threadIdx.x;
  const int lane = tid & 63;
  const int wv = tid >> 6;      // 0..7
  const int wm = wv >> 2;       // 0..1 (A half)
  const int wn = wv & 3;        // 0..3
  const int l31 = lane & 31;
  const int hi = lane >> 5;     // k-half select

  // staging: linear LDS dest; content[o] = logical[o ^ f(row)], row = o>>7,
  // f(row) = ((row&7) ^ ((row>>3)&3)) << 4. f is invariant across the two
  // rows (srow, srow+64) a thread stages: (row>>3)&3 unchanged by +64.
  const int srow = tid >> 3;
  const int scolb = ((tid & 7) * 16) ^
                    (((((tid >> 3) & 7) ^ ((tid >> 6) & 3))) << 4);
  const unsigned short* Abase = A + offA + (long)tm * lda + (scolb >> 1);
  const unsigned short* Bbase = B + offB + (long)tn * ldb + (scolb >> 1);
  const int ldsw = wv * 1024;

  // fragment reads: row = blk*32 + l31 -> f depends only on l31:
  // f3 = (l31&7) ^ ((l31>>3)&3)  (blk*32 contributes 0 to both terms mod 8/4)
  const int fl = ((l31 & 7) ^ ((l31 >> 3) & 3)) << 4;
  // per-(ks) byte cols for this lane's 16B fragment (k = ks*16 + hi*8 .. +8)
  int colswz[4];
  #pragma unroll
  for (int ks = 0; ks < 4; ++ks) colswz[ks] = (ks * 32 + hi * 16) ^ fl;

  f32x16 acc[4][2];
  #pragma unroll
  for (int i = 0; i < 4; ++i)
    #pragma unroll
    for (int j = 0; j < 2; ++j)
      #pragma unroll
      for (int e = 0; e < 16; ++e) acc[i][j][e] = 0.f;

  auto stageAh = [&](int t, int h) {       // one A half-tile (2 loads)
    const int buf = t & 1;
    #pragma unroll
    for (int i = 0; i < 2; ++i)
      gl_lds16(Abase + (long)(h * 128 + srow + i * 64) * lda + t * 64,
               &LDS[buf * 32768 + h * 16384 + i * 8192 + ldsw]);
  };
  auto stageBh = [&](int t, int h) {       // one B half-tile (2 loads)
    const int buf = t & 1;
    #pragma unroll
    for (int i = 0; i < 2; ++i)
      gl_lds16(Bbase + (long)(h * 128 + srow + i * 64) * ldb + t * 64,
               &LDS[65536 + buf * 32768 + h * 16384 + i * 8192 + ldsw]);
  };

  // prologue: tiles 0,1 staged (8 loads each); wait tile 0 only
  stageAh(0, 0); stageAh(0, 1); stageBh(0, 0); stageBh(0, 1);
  stageAh(1, 0); stageAh(1, 1); stageBh(1, 0); stageBh(1, 1);
  asm volatile("s_waitcnt vmcnt(8)" ::: "memory");
  __builtin_amdgcn_s_barrier();

  for (int t = 0; t < NT; ++t) {
    const unsigned char* aB = &LDS[(t & 1) * 32768 + wm * 16384];
    const unsigned char* bB = &LDS[65536 + (t & 1) * 32768 + (wn >> 1) * 16384];
    const int brow = (wn & 1) * 64;
    bf16x8 bfrag[2][4];
    #pragma unroll
    for (int j = 0; j < 4; ++j) {        // phase j computes row-block rb=j
      bf16x8 afr[4];
      #pragma unroll
      for (int ks = 0; ks < 4; ++ks)
        afr[ks] = *(const bf16x8*)(aB + (j * 32 + l31) * 128 + colswz[ks]);
      if (j == 0) {
        #pragma unroll
        for (int nb = 0; nb < 2; ++nb)
          #pragma unroll
          for (int ks = 0; ks < 4; ++ks)
            bfrag[nb][ks] = *(const bf16x8*)(bB + (brow + nb * 32 + l31) * 128 + colswz[ks]);
        if (t > 0 && t + 1 < NT) stageAh(t + 1, 0);
      } else if (j == 1) {
        if (t > 0 && t + 1 < NT) stageAh(t + 1, 1);
      } else if (j == 2) {
        if (t + 2 < NT) stageBh(t + 2, 0);
      } else {
        if (t + 2 < NT) stageBh(t + 2, 1);
      }
      asm volatile("s_waitcnt lgkmcnt(0)" ::: "memory");
      __builtin_amdgcn_sched_barrier(0);
      if (j == 1) {
        __builtin_amdgcn_s_barrier();          // pre-MFMA: B(t)-slot protection
      } else if (j == 3) {
        if (t >= NT - 2) { asm volatile("s_waitcnt vmcnt(0)" ::: "memory"); }
        else             { asm volatile("s_waitcnt vmcnt(4)" ::: "memory"); }
        __builtin_amdgcn_sched_barrier(0);
        __builtin_amdgcn_s_barrier();          // pre-MFMA: tile boundary
      }
      __builtin_amdgcn_s_setprio(1);
      #pragma unroll
      for (int ks = 0; ks < 4; ++ks)
        #pragma unroll
        for (int nb = 0; nb < 2; ++nb)
          acc[j][nb] = __builtin_amdgcn_mfma_f32_32x32x16_bf16(
              afr[ks], bfrag[nb][ks], acc[j][nb], 0, 0, 0);
      __builtin_amdgcn_s_setprio(0);
    }
  }
  // Post-loop: LDS reusable per-wave (same argument as R12).

  // epilogue: 32x32 C/D map (R4-verified): col=l31, row=(r&3)+8*(r>>2)+4*hi
  const int which = SPLIT3 ? (tn >> 12) : 0;
  const float* bp = SPLIT3 ? (which == 0 ? b0 : (which == 1 ? b1 : b2)) : b0;
  void* Cp = SPLIT3 ? (which == 0 ? C0 : (which == 1 ? C1 : C2)) : C0;
  const int tnn = SPLIT3 ? (tn & 4095) : tn;

  if (CF32) {
    // f32 path (final GEMM): nontemporal 128B-segment stores
    #pragma unroll
    for (int nb = 0; nb < 2; ++nb) {
      const int col = tnn + wn * 64 + nb * 32 + l31;
      const float bv = HAS_BIAS ? bp[col] : 0.f;
      #pragma unroll
      for (int rb = 0; rb < 4; ++rb)
        #pragma unroll
        for (int r = 0; r < 16; ++r) {
          const int row = tm + wm * 128 + rb * 32 + (r & 3) + ((r >> 2) << 3) + hi * 4;
          __builtin_nontemporal_store(acc[rb][nb][r] * alpha + bv,
                                      &((float*)Cp)[offC + (long)row * ldc + col]);
        }
    }
  } else if (SPLIT3 && which == 2) {
    // v group: write TRANSPOSED into vT (B*H, 512d, 512t).
    unsigned short* lw = (unsigned short*)&LDS[wv * 16384];
    #pragma unroll
    for (int nb = 0; nb < 2; ++nb) {
      const int dl = nb * 32 + l31;
      const float bv = HAS_BIAS ? bp[tnn + wn * 64 + dl] : 0.f;
      #pragma unroll
      for (int rb = 0; rb < 4; ++rb)
        #pragma unroll
        for (int r = 0; r < 16; ++r) {
          const int tl = rb * 32 + (r & 3) + ((r >> 2) << 3) + hi * 4;
          lw[dl * 128 + (tl ^ ((dl & 7) << 4))] = f2bf(acc[rb][nb][r] * alpha + bv);
        }
    }
    asm volatile("s_waitcnt lgkmcnt(0)" ::: "memory");
    __builtin_amdgcn_sched_barrier(0);
    const int b = tm >> 9, hh = tnn >> 9;
    const int dbase = (tnn & 511) + wn * 64;
    const int tbase = (tm & 511) + wm * 128;
    unsigned short* vTg = (unsigned short*)C2 +
                          ((long)(b * 8 + hh) * 512 + dbase) * 512 + tbase;
    const int dr = lane >> 4, t8 = (lane & 15) * 8;
    #pragma unroll
    for (int i = 0; i < 16; ++i) {
      const int dl = i * 4 + dr;
      short8 val = *(const short8*)&lw[dl * 128 + (t8 ^ ((dl & 7) << 4))];
      __builtin_nontemporal_store(val, (short8*)(vTg + (long)dl * 512 + t8));
    }
  } else {
    // bf16 path: per-wave LDS transpose -> fully coalesced 128B row segments
    unsigned short* lw = (unsigned short*)&LDS[wv * 16384];  // private 16KB
    #pragma unroll
    for (int nb = 0; nb < 2; ++nb) {
      const float bv = HAS_BIAS ? bp[tnn + wn * 64 + nb * 32 + l31] : 0.f;
      #pragma unroll
      for (int rb = 0; rb < 4; ++rb)
        #pragma unroll
        for (int r = 0; r < 16; ++r) {
          const int rl = rb * 32 + (r & 3) + ((r >> 2) << 3) + hi * 4;
          lw[rl * 64 + nb * 32 + l31] = f2bf(acc[rb][nb][r] * alpha + bv);
        }
    }
    asm volatile("s_waitcnt lgkmcnt(0)" ::: "memory");
    __builtin_amdgcn_sched_barrier(0);
    unsigned short* Cg = (unsigned short*)Cp + offC +
                         (long)(tm + wm * 128) * ldc + tnn + wn * 64;
    const int rr = lane >> 3, cc = (lane & 7) * 8;
    #pragma unroll
    for (int i = 0; i < 16; ++i) {
      short8 val = *(const short8*)&lw[(i * 8 + rr) * 64 + cc];
      *(short8*)(Cg + (long)(i * 8 + rr) * ldc + cc) = val;
    }
  }
}

// ============================================================================
// merged f32 -> bf16 convert over up to 4 consecutive dst ranges
// ============================================================================
__global__ __launch_bounds__(256)
void cvt_multi(const float* __restrict__ s0, long n0,
               const float* __restrict__ s1, long n1,
               const float* __restrict__ s2, long n2,
               const float* __restrict__ s3, long n3,
               unsigned short* __restrict__ dst, long n8)
{
  long i = (long)blockIdx.x * 256 + threadIdx.x;
  const long stride = (long)gridDim.x * 256;
  for (; i < n8; i += stride) {
    long e = i * 8;
    const float* src;
    if (e < n0)                    src = s0 + e;
    else if (e < n0 + n1)          src = s1 + (e - n0);
    else if (e < n0 + n1 + n2)     src = s2 + (e - n0 - n1);
    else                           src = s3 + (e - n0 - n1 - n2);
    f32x4 v0 = *(const f32x4*)(src);
    f32x4 v1 = *(const f32x4*)(src + 4);
    uint4v o;
    o[0] = cvt_pk_bf16(v0[0], v0[1]);
    o[1] = cvt_pk_bf16(v0[2], v0[3]);
    o[2] = cvt_pk_bf16(v1[0], v1[1]);
    o[3] = cvt_pk_bf16(v1[2], v1[3]);
    *(uint4v*)(dst + e) = o;
  }
}

// In-place LayerNorm over rows of 512 bf16 for q then k (merged). One wave/row.
__global__ __launch_bounds__(256)
void ln_rows2(unsigned short* __restrict__ q, const float* __restrict__ gq,
              const float* __restrict__ bq_, unsigned short* __restrict__ k,
              const float* __restrict__ gk, const float* __restrict__ bk_,
              int rows_per_tensor)
{
  int row = blockIdx.x * 4 + ((int)threadIdx.x >> 6);
  const int lane = (int)threadIdx.x & 63;
  unsigned short* base = q;
  const float* g = gq;
  const float* b = bq_;
  if (row >= rows_per_tensor) { row -= rows_per_tensor; base = k; g = gk; b = bk_; }
  unsigned short* p = base + (long)row * 512 + lane * 8;
  short8 rv = *(const short8*)p;
  float x[8];
  #pragma unroll
  for (int j = 0; j < 8; ++j) x[j] = bf2f((unsigned short)rv[j]);
  float s = 0.f;
  #pragma unroll
  for (int j = 0; j < 8; ++j) s += x[j];
  #pragma unroll
  for (int off = 32; off > 0; off >>= 1) s += __shfl_xor(s, off, 64);
  float mu = s * (1.f / 512.f);
  float vs = 0.f;
  #pragma unroll
  for (int j = 0; j < 8; ++j) { float d = x[j] - mu; vs += d * d; }
  #pragma unroll
  for (int off = 32; off > 0; off >>= 1) vs += __shfl_xor(vs, off, 64);
  float rs = rsqrtf(vs * (1.f / 512.f) + 1e-5f);
  f32x4 gv0 = *(const f32x4*)(g + lane * 8);
  f32x4 gv1 = *(const f32x4*)(g + lane * 8 + 4);
  f32x4 bv0 = *(const f32x4*)(b + lane * 8);
  f32x4 bv1 = *(const f32x4*)(b + lane * 8 + 4);
  short8 ov;
  #pragma unroll
  for (int j = 0; j < 4; ++j) ov[j] = (short)f2bf((x[j] - mu) * rs * gv0[j] + bv0[j]);
  #pragma unroll
  for (int j = 0; j < 4; ++j) ov[4 + j] = (short)f2bf((x[4 + j] - mu) * rs * gv1[j] + bv1[j]);
  *(short8*)p = ov;
}

// w = (val * gelu_exact(gate)) / max(||.||2, 1e-12); h rows are 1024 (val|gate)
__global__ __launch_bounds__(256)
void gate_norm(const unsigned short* __restrict__ h, unsigned short* __restrict__ w)
{
  const int row = blockIdx.x * 4 + ((int)threadIdx.x >> 6);
  const int lane = (int)threadIdx.x & 63;
  const unsigned short* hp = h + (long)row * 1024 + lane * 8;
  short8 vv = *(const short8*)hp;
  short8 gg = *(const short8*)(hp + 512);
  float wv[8];
  float ssq = 0.f;
  #pragma unroll
  for (int j = 0; j < 8; ++j) {
    float val = bf2f((unsigned short)vv[j]);
    float gt  = bf2f((unsigned short)gg[j]);
    float tt  = val * (0.5f * gt * (1.f + erff(gt * 0.70710678118654752f)));
    wv[j] = tt;
    ssq += tt * tt;
  }
  #pragma unroll
  for (int off = 32; off > 0; off >>= 1) ssq += __shfl_xor(ssq, off, 64);
  float scale = 1.f / fmaxf(sqrtf(ssq), 1e-12f);
  short8 ov;
  #pragma unroll
  for (int j = 0; j < 8; ++j) ov[j] = (short)f2bf(wv[j] * scale);
  *(short8*)(w + (long)row * 512 + lane * 8) = ov;
}

extern "C" void kernel_launch(void* const* d_in, const int* in_sizes, int n_in,
                              void* d_out, int out_size, void* d_ws, size_t ws_size,
                              hipStream_t stream)
{
  (void)in_sizes; (void)n_in; (void)out_size; (void)ws_size;
  const float* x   = (const float*)d_in[0];
  const float* Wq  = (const float*)d_in[1];
  const float* bq  = (const float*)d_in[2];
  const float* Wk  = (const float*)d_in[3];
  const float* bk  = (const float*)d_in[4];
  const float* Wv  = (const float*)d_in[5];
  const float* bv  = (const float*)d_in[6];
  const float* g_q = (const float*)d_in[7];
  const float* b_q = (const float*)d_in[8];
  const float* g_k = (const float*)d_in[9];
  const float* b_k = (const float*)d_in[10];
  const float* Wg  = (const float*)d_in[11];
  const float* bg  = (const float*)d_in[12];
  const float* Wo  = (const float*)d_in[13];
  const float* bo  = (const float*)d_in[14];
  float* out = (float*)d_out;

  const long NE  = 33554432L;   // B*S*E
  const long NE2 = NE / 2;      // 4096*4096
  unsigned short* ws    = (unsigned short*)d_ws;
  unsigned short* xb    = ws;                    // [0, NE)
  unsigned short* Wqkv  = ws + NE;               // [NE, 2.5NE) Wq|Wk|Wv
  unsigned short* qbuf  = ws + NE + 3 * NE2;     // [2.5NE, 3.5NE)
  unsigned short* kbuf  = qbuf + NE;             // [3.5NE, 4.5NE)
  unsigned short* vT    = kbuf + NE;             // [4.5NE, 5.5NE) (B*H,512d,512t)
  unsigned short* Wgb   = Wqkv;                  // 1024x512 (after proj)
  unsigned short* Wob   = Wqkv + 524288;         // 4096x4096 (after proj)
  unsigned short* sbuf  = xb;                    // scores (x dead after proj)
  unsigned short* hbuf  = qbuf;                  // spans qbuf+kbuf (dead after scores)
  unsigned short* wbuf  = xb;                    // scores dead after h-GEMM
  unsigned short* obuf  = kbuf;                  // h dead after gate_norm

  dim3 blk256(256), blk512(512);
  const float isq = 0.044194173824159216f;  // 1/sqrt(512)

  // one merged convert: x | Wq | Wk | Wv  ->  ws[0 .. 2.5NE)
  cvt_multi<<<20480, blk256, 0, stream>>>(x, NE, Wq, NE2, Wk, NE2, Wv, NE2,
                                          ws, (NE + 3 * NE2) / 8);

  // merged q|k|v projection: split-3 epilogue; v written transposed into vT
  gemm256<0, 1, 0, 1><<<1536, blk512, 0, stream>>>(
      xb, Wqkv, bq, bk, bv, qbuf, kbuf, vT,
      4096, 4096, 4096, 4096, 48, 1.f,
      0L, 0L, 1, 0L, 0L, 1, 0L, 0L, 1);

  // Wqkv dead -> convert Wg, Wo into its region (one launch)
  cvt_multi<<<8192, blk256, 0, stream>>>(Wg, 524288L, Wo, NE2,
                                         nullptr, 0L, nullptr, 0L,
                                         Wgb, (524288L + NE2) / 8);

  // layernorm q and k (merged)
  ln_rows2<<<32768, blk256, 0, stream>>>(qbuf, g_q, b_q, kbuf, g_k, b_k, 65536);

  // scores = q @ k^T / sqrt(HD), per (b,h) -> sbuf (=xb)
  gemm256<1, 0, 0, 0><<<dim3(4, 1, 128), blk512, 0, stream>>>(
      qbuf, kbuf, nullptr, nullptr, nullptr, sbuf, nullptr, nullptr,
      512, 4096, 4096, 512, 2, isq,
      2097152L, 512L, 8,
      2097152L, 512L, 8,
      262144L, 0L, 1);

  // h = scores @ Wg^T + bg -> hbuf (=qbuf..kbuf)
  gemm256<1, 0, 0, 1><<<dim3(8, 1, 128), blk512, 0, stream>>>(
      sbuf, Wgb, bg, nullptr, nullptr, hbuf, nullptr, nullptr,
      512, 512, 512, 1024, 4, 1.f,
      262144L, 0L, 1,
      0L, 0L, 1,
      524288L, 0L, 1);

  gate_norm<<<16384, blk256, 0, stream>>>(hbuf, wbuf);

  // attn_out = w @ vT^T -> obuf (=kbuf), (B,S,E) layout
  gemm256<1, 0, 0, 0><<<dim3(4, 1, 128), blk512, 0, stream>>>(
      wbuf, vT, nullptr, nullptr, nullptr, obuf, nullptr, nullptr,
      512, 512, 512, 4096, 2, 1.f,
      262144L, 0L, 1,
      262144L, 0L, 1,
      2097152L, 512L, 8);

  // final = attn_out @ Wo^T + bo -> d_out (f32, nontemporal)
  gemm256<0, 0, 1, 1><<<512, blk512, 0, stream>>>(
      obuf, Wob, bo, nullptr, nullptr, out, nullptr, nullptr,
      4096, 4096, 4096, 4096, 16, 1.f,
      0L, 0L, 1, 0L, 0L, 1, 0L, 0L, 1);
}

// Round 14
// 1214.661 us; speedup vs baseline: 1.0588x; 1.0588x over previous
//
#include <hip/hip_runtime.h>
#include <math.h>

typedef __bf16 bf16x8 __attribute__((ext_vector_type(8)));
typedef float f32x4 __attribute__((ext_vector_type(4)));
typedef short short8 __attribute__((ext_vector_type(8)));
typedef unsigned int uint4v __attribute__((ext_vector_type(4)));

__device__ __forceinline__ float bf2f(unsigned short u) {
  union { unsigned int i; float f; } v; v.i = ((unsigned int)u) << 16; return v.f;
}
__device__ __forceinline__ unsigned short f2bf(float f) {
  union { float fl; unsigned int i; } v; v.fl = f;
  unsigned int x = v.i;
  return (unsigned short)((x + 0x7FFFu + ((x >> 16) & 1u)) >> 16);  // RNE
}
__device__ __forceinline__ unsigned int cvt_pk_bf16(float lo, float hi) {
  unsigned int r;
  asm("v_cvt_pk_bf16_f32 %0, %1, %2" : "=v"(r) : "v"(lo), "v"(hi));
  return r;
}
// async global->LDS, 16B per lane. lds ptr wave-uniform (HW adds lane*16).
__device__ __forceinline__ void gl_lds16(const unsigned short* g, void* l) {
  __builtin_amdgcn_global_load_lds(
      (const __attribute__((address_space(1))) unsigned int*)g,
      (__attribute__((address_space(3))) unsigned int*)l, 16, 0, 0);
}

// ============================================================================
// 256x256 bf16 GEMM, 16x16x32 MFMA. R12-proven configuration (best measured):
// minimal-barrier drift schedule (2 barriers/tile, both pre-MFMA), counted
// vmcnt(4), 0 K-loop bank conflicts, LDS-transpose bf16 epilogue, batched
// z-major XCD-chunked swizzle, SPLIT3 q|k|vT routing (v written transposed).
// Hazard ledger (per tile t):
//  - Each phase: wave's own lgkmcnt(0) drains its ds_reads before its MFMA
//    AND before it can reach the next barrier.
//  - j1 barrier (pre-MFMA(2)): every wave past it has executed j0's
//    lgkmcnt(0) -> all B(t) frag reads drained before any j2 stageB(t+2)
//    DMA targets B(t)'s slot.
//  - j3 barrier (pre-MFMA(6), after vmcnt): every wave drained through
//    tile t+1's staging loads (FIFO: B(t+1)4 A(t+1)4 | B(t+2)4 -> vmcnt(4))
//    and its own A(t)/B(t) ds_reads -> tile t+1 buffers valid, A(t) slot
//    safe for next j0's stageA(t+2).
// ============================================================================
template<int BATCH, int SPLIT3, int CF32, int HAS_BIAS>
__global__ __launch_bounds__(512)
void gemm256(const unsigned short* __restrict__ A,
             const unsigned short* __restrict__ B,
             const float* __restrict__ b0, const float* __restrict__ b1,
             const float* __restrict__ b2,
             void* __restrict__ C0, void* __restrict__ C1, void* __restrict__ C2,
             int K, int lda, int ldb, int ldc, int nbn, float alpha,
             long sAo, long sAi, int nAi,
             long sBo, long sBi, int nBi,
             long sCo, long sCi, int nCi)
{
  __shared__ alignas(16) unsigned char LDS[131072];
  const int NT = K >> 6;   // even, >= 2

  int tm, tn;
  long offA = 0, offB = 0, offC = 0;
  if (BATCH) {
    // XCD-chunked over z-major flatten (total blocks % 8 == 0):
    // consecutive work-items (same batch) land on the same XCD's L2.
    const int nbx = (int)gridDim.x;
    const int nf = nbx * (int)gridDim.z;
    const int f = (int)blockIdx.z * nbx + (int)blockIdx.x;
    const int s = (f & 7) * (nf >> 3) + (f >> 3);
    const int bx = s % nbx;
    const int z = s / nbx;
    tm = (bx / nbn) * 256;
    tn = (bx % nbn) * 256;
    offA = (long)(z / nAi) * sAo + (long)(z % nAi) * sAi;
    offB = (long)(z / nBi) * sBo + (long)(z % nBi) * sBi;
    offC = (long)(z / nCi) * sCo + (long)(z % nCi) * sCi;
  } else {
    const int nwg = (int)gridDim.x;
    const int bid = (int)blockIdx.x;
    const int s = (bid & 7) * (nwg >> 3) + (bid >> 3);
    const int sTile = s >> 4, w = s & 15;
    const int snb = nbn >> 2;
    tm = ((sTile / snb) * 4 + (w >> 2)) * 256;
    tn = ((sTile % snb) * 4 + (w & 3)) * 256;
  }

  const int tid = (int)threadIdx.x;
  const int lane = tid & 63;
  const int wv = tid >> 6;      // 0..7
  const int wm = wv >> 2;       // 0..1 (A half)
  const int wn = wv & 3;        // 0..3
  const int l16 = lane & 15;
  const int kg = lane >> 4;

  // staging: linear LDS dest; content[o] = logical[o ^ ((row&7)<<4)], row=o>>7
  const int srow = tid >> 3;
  const int scolb = ((tid & 7) * 16) ^ (((tid >> 3) & 7) << 4);
  const unsigned short* Abase = A + offA + (long)tm * lda + (scolb >> 1);
  const unsigned short* Bbase = B + offB + (long)tn * ldb + (scolb >> 1);
  const int ldsw = wv * 1024;

  // frag read cols (full-XOR swizzle on byte col, row&7 == l16&7)
  const int colswz0 = (kg * 16) ^ ((l16 & 7) << 4);
  const int colswz1 = (64 + kg * 16) ^ ((l16 & 7) << 4);

  f32x4 acc[8][4];
  #pragma unroll
  for (int i = 0; i < 8; ++i)
    #pragma unroll
    for (int j = 0; j < 4; ++j)
      #pragma unroll
      for (int e = 0; e < 4; ++e) acc[i][j][e] = 0.f;

  auto stageAh = [&](int t, int h) {       // one A half-tile (2 loads)
    const int buf = t & 1;
    #pragma unroll
    for (int i = 0; i < 2; ++i)
      gl_lds16(Abase + (long)(h * 128 + srow + i * 64) * lda + t * 64,
               &LDS[buf * 32768 + h * 16384 + i * 8192 + ldsw]);
  };
  auto stageBh = [&](int t, int h) {       // one B half-tile (2 loads)
    const int buf = t & 1;
    #pragma unroll
    for (int i = 0; i < 2; ++i)
      gl_lds16(Bbase + (long)(h * 128 + srow + i * 64) * ldb + t * 64,
               &LDS[65536 + buf * 32768 + h * 16384 + i * 8192 + ldsw]);
  };

  // prologue: tiles 0,1 staged (8 loads each); wait tile 0 only
  stageAh(0, 0); stageAh(0, 1); stageBh(0, 0); stageBh(0, 1);
  stageAh(1, 0); stageAh(1, 1); stageBh(1, 0); stageBh(1, 1);
  asm volatile("s_waitcnt vmcnt(8)" ::: "memory");
  __builtin_amdgcn_s_barrier();

  for (int t = 0; t < NT; ++t) {
    const unsigned char* aB = &LDS[(t & 1) * 32768 + wm * 16384];
    const unsigned char* bB = &LDS[65536 + (t & 1) * 32768 + (wn >> 1) * 16384];
    const int brow = (wn & 1) * 64;
    bf16x8 bfrag[4][2];
    #pragma unroll
    for (int j = 0; j < 4; ++j) {
      bf16x8 a0k0 = *(const bf16x8*)(aB + ((2 * j + 0) * 16 + l16) * 128 + colswz0);
      bf16x8 a0k1 = *(const bf16x8*)(aB + ((2 * j + 0) * 16 + l16) * 128 + colswz1);
      bf16x8 a1k0 = *(const bf16x8*)(aB + ((2 * j + 1) * 16 + l16) * 128 + colswz0);
      bf16x8 a1k1 = *(const bf16x8*)(aB + ((2 * j + 1) * 16 + l16) * 128 + colswz1);
      if (j == 0) {
        #pragma unroll
        for (int ni = 0; ni < 4; ++ni) {
          bfrag[ni][0] = *(const bf16x8*)(bB + (brow + ni * 16 + l16) * 128 + colswz0);
          bfrag[ni][1] = *(const bf16x8*)(bB + (brow + ni * 16 + l16) * 128 + colswz1);
        }
        if (t > 0 && t + 1 < NT) stageAh(t + 1, 0);
      } else if (j == 1) {
        if (t > 0 && t + 1 < NT) stageAh(t + 1, 1);
      } else if (j == 2) {
        if (t + 2 < NT) stageBh(t + 2, 0);
      } else {
        if (t + 2 < NT) stageBh(t + 2, 1);
      }
      asm volatile("s_waitcnt lgkmcnt(0)" ::: "memory");
      __builtin_amdgcn_sched_barrier(0);
      if (j == 1) {
        __builtin_amdgcn_s_barrier();          // pre-MFMA: B(t)-slot protection
      } else if (j == 3) {
        if (t >= NT - 2) { asm volatile("s_waitcnt vmcnt(0)" ::: "memory"); }
        else             { asm volatile("s_waitcnt vmcnt(4)" ::: "memory"); }
        __builtin_amdgcn_sched_barrier(0);
        __builtin_amdgcn_s_barrier();          // pre-MFMA: tile boundary
      }
      __builtin_amdgcn_s_setprio(1);
      #pragma unroll
      for (int ni = 0; ni < 4; ++ni) {
        acc[2 * j + 0][ni] = __builtin_amdgcn_mfma_f32_16x16x32_bf16(a0k0, bfrag[ni][0], acc[2 * j + 0][ni], 0, 0, 0);
        acc[2 * j + 0][ni] = __builtin_amdgcn_mfma_f32_16x16x32_bf16(a0k1, bfrag[ni][1], acc[2 * j + 0][ni], 0, 0, 0);
        acc[2 * j + 1][ni] = __builtin_amdgcn_mfma_f32_16x16x32_bf16(a1k0, bfrag[ni][0], acc[2 * j + 1][ni], 0, 0, 0);
        acc[2 * j + 1][ni] = __builtin_amdgcn_mfma_f32_16x16x32_bf16(a1k1, bfrag[ni][1], acc[2 * j + 1][ni], 0, 0, 0);
      }
      __builtin_amdgcn_s_setprio(0);
    }
  }
  // Post-loop: every wave's ds_reads are drained (its own last lgkmcnt(0)),
  // and all waves passed the last tile's pre-MFMA barrier; remaining MFMA
  // work is register-only -> LDS safely reusable per-wave for the epilogue.

  // epilogue: C/D layout col=lane&15, row=(lane>>4)*4 + j (m89-verified)
  const int which = SPLIT3 ? (tn >> 12) : 0;
  const float* bp = SPLIT3 ? (which == 0 ? b0 : (which == 1 ? b1 : b2)) : b0;
  void* Cp = SPLIT3 ? (which == 0 ? C0 : (which == 1 ? C1 : C2)) : C0;
  const int tnn = SPLIT3 ? (tn & 4095) : tn;

  if (CF32) {
    // f32 path (final GEMM): nontemporal direct stores (never re-read)
    #pragma unroll
    for (int ni = 0; ni < 4; ++ni) {
      const int col = tnn + wn * 64 + ni * 16 + l16;
      const float bv = HAS_BIAS ? bp[col] : 0.f;
      #pragma unroll
      for (int mi = 0; mi < 8; ++mi)
        #pragma unroll
        for (int jj = 0; jj < 4; ++jj) {
          const int row = tm + wm * 128 + mi * 16 + kg * 4 + jj;
          __builtin_nontemporal_store(acc[mi][ni][jj] * alpha + bv,
                                      &((float*)Cp)[offC + (long)row * ldc + col]);
        }
    }
  } else if (SPLIT3 && which == 2) {
    // v group: write TRANSPOSED into vT (B*H, 512d, 512t).
    unsigned short* lw = (unsigned short*)&LDS[wv * 16384];
    #pragma unroll
    for (int ni = 0; ni < 4; ++ni) {
      const int dl = ni * 16 + l16;
      const float bv = HAS_BIAS ? bp[tnn + wn * 64 + dl] : 0.f;
      #pragma unroll
      for (int mi = 0; mi < 8; ++mi)
        #pragma unroll
        for (int jj = 0; jj < 4; ++jj) {
          const int tl = mi * 16 + kg * 4 + jj;
          lw[dl * 128 + (tl ^ ((dl & 7) << 4))] = f2bf(acc[mi][ni][jj] * alpha + bv);
        }
    }
    asm volatile("s_waitcnt lgkmcnt(0)" ::: "memory");
    __builtin_amdgcn_sched_barrier(0);
    const int b = tm >> 9, hh = tnn >> 9;
    const int dbase = (tnn & 511) + wn * 64;
    const int tbase = (tm & 511) + wm * 128;
    unsigned short* vTg = (unsigned short*)C2 +
                          ((long)(b * 8 + hh) * 512 + dbase) * 512 + tbase;
    const int dr = lane >> 4, t8 = (lane & 15) * 8;
    #pragma unroll
    for (int i = 0; i < 16; ++i) {
      const int dl = i * 4 + dr;
      short8 val = *(const short8*)&lw[dl * 128 + (t8 ^ ((dl & 7) << 4))];
      __builtin_nontemporal_store(val, (short8*)(vTg + (long)dl * 512 + t8));
    }
  } else {
    // bf16 path: per-wave LDS transpose -> fully coalesced 128B row segments
    unsigned short* lw = (unsigned short*)&LDS[wv * 16384];  // private 16KB
    #pragma unroll
    for (int ni = 0; ni < 4; ++ni) {
      const float bv = HAS_BIAS ? bp[tnn + wn * 64 + ni * 16 + l16] : 0.f;
      #pragma unroll
      for (int mi = 0; mi < 8; ++mi)
        #pragma unroll
        for (int jj = 0; jj < 4; ++jj)
          lw[(mi * 16 + kg * 4 + jj) * 64 + ni * 16 + l16] =
              f2bf(acc[mi][ni][jj] * alpha + bv);
    }
    asm volatile("s_waitcnt lgkmcnt(0)" ::: "memory");
    __builtin_amdgcn_sched_barrier(0);
    unsigned short* Cg = (unsigned short*)Cp + offC +
                         (long)(tm + wm * 128) * ldc + tnn + wn * 64;
    const int rr = lane >> 3, cc = (lane & 7) * 8;
    #pragma unroll
    for (int i = 0; i < 16; ++i) {
      short8 val = *(const short8*)&lw[(i * 8 + rr) * 64 + cc];
      *(short8*)(Cg + (long)(i * 8 + rr) * ldc + cc) = val;
    }
  }
}

// ============================================================================
// merged f32 -> bf16 convert over up to 4 consecutive dst ranges
// ============================================================================
__global__ __launch_bounds__(256)
void cvt_multi(const float* __restrict__ s0, long n0,
               const float* __restrict__ s1, long n1,
               const float* __restrict__ s2, long n2,
               const float* __restrict__ s3, long n3,
               unsigned short* __restrict__ dst, long n8)
{
  long i = (long)blockIdx.x * 256 + threadIdx.x;
  const long stride = (long)gridDim.x * 256;
  for (; i < n8; i += stride) {
    long e = i * 8;
    const float* src;
    if (e < n0)                    src = s0 + e;
    else if (e < n0 + n1)          src = s1 + (e - n0);
    else if (e < n0 + n1 + n2)     src = s2 + (e - n0 - n1);
    else                           src = s3 + (e - n0 - n1 - n2);
    f32x4 v0 = *(const f32x4*)(src);
    f32x4 v1 = *(const f32x4*)(src + 4);
    uint4v o;
    o[0] = cvt_pk_bf16(v0[0], v0[1]);
    o[1] = cvt_pk_bf16(v0[2], v0[3]);
    o[2] = cvt_pk_bf16(v1[0], v1[1]);
    o[3] = cvt_pk_bf16(v1[2], v1[3]);
    *(uint4v*)(dst + e) = o;
  }
}

// In-place LayerNorm over rows of 512 bf16 for q then k (merged). One wave/row.
__global__ __launch_bounds__(256)
void ln_rows2(unsigned short* __restrict__ q, const float* __restrict__ gq,
              const float* __restrict__ bq_, unsigned short* __restrict__ k,
              const float* __restrict__ gk, const float* __restrict__ bk_,
              int rows_per_tensor)
{
  int row = blockIdx.x * 4 + ((int)threadIdx.x >> 6);
  const int lane = (int)threadIdx.x & 63;
  unsigned short* base = q;
  const float* g = gq;
  const float* b = bq_;
  if (row >= rows_per_tensor) { row -= rows_per_tensor; base = k; g = gk; b = bk_; }
  unsigned short* p = base + (long)row * 512 + lane * 8;
  short8 rv = *(const short8*)p;
  float x[8];
  #pragma unroll
  for (int j = 0; j < 8; ++j) x[j] = bf2f((unsigned short)rv[j]);
  float s = 0.f;
  #pragma unroll
  for (int j = 0; j < 8; ++j) s += x[j];
  #pragma unroll
  for (int off = 32; off > 0; off >>= 1) s += __shfl_xor(s, off, 64);
  float mu = s * (1.f / 512.f);
  float vs = 0.f;
  #pragma unroll
  for (int j = 0; j < 8; ++j) { float d = x[j] - mu; vs += d * d; }
  #pragma unroll
  for (int off = 32; off > 0; off >>= 1) vs += __shfl_xor(vs, off, 64);
  float rs = rsqrtf(vs * (1.f / 512.f) + 1e-5f);
  f32x4 gv0 = *(const f32x4*)(g + lane * 8);
  f32x4 gv1 = *(const f32x4*)(g + lane * 8 + 4);
  f32x4 bv0 = *(const f32x4*)(b + lane * 8);
  f32x4 bv1 = *(const f32x4*)(b + lane * 8 + 4);
  short8 ov;
  #pragma unroll
  for (int j = 0; j < 4; ++j) ov[j] = (short)f2bf((x[j] - mu) * rs * gv0[j] + bv0[j]);
  #pragma unroll
  for (int j = 0; j < 4; ++j) ov[4 + j] = (short)f2bf((x[4 + j] - mu) * rs * gv1[j] + bv1[j]);
  *(short8*)p = ov;
}

// w = (val * gelu_exact(gate)) / max(||.||2, 1e-12); h rows are 1024 (val|gate)
__global__ __launch_bounds__(256)
void gate_norm(const unsigned short* __restrict__ h, unsigned short* __restrict__ w)
{
  const int row = blockIdx.x * 4 + ((int)threadIdx.x >> 6);
  const int lane = (int)threadIdx.x & 63;
  const unsigned short* hp = h + (long)row * 1024 + lane * 8;
  short8 vv = *(const short8*)hp;
  short8 gg = *(const short8*)(hp + 512);
  float wv[8];
  float ssq = 0.f;
  #pragma unroll
  for (int j = 0; j < 8; ++j) {
    float val = bf2f((unsigned short)vv[j]);
    float gt  = bf2f((unsigned short)gg[j]);
    float tt  = val * (0.5f * gt * (1.f + erff(gt * 0.70710678118654752f)));
    wv[j] = tt;
    ssq += tt * tt;
  }
  #pragma unroll
  for (int off = 32; off > 0; off >>= 1) ssq += __shfl_xor(ssq, off, 64);
  float scale = 1.f / fmaxf(sqrtf(ssq), 1e-12f);
  short8 ov;
  #pragma unroll
  for (int j = 0; j < 8; ++j) ov[j] = (short)f2bf(wv[j] * scale);
  *(short8*)(w + (long)row * 512 + lane * 8) = ov;
}

extern "C" void kernel_launch(void* const* d_in, const int* in_sizes, int n_in,
                              void* d_out, int out_size, void* d_ws, size_t ws_size,
                              hipStream_t stream)
{
  (void)in_sizes; (void)n_in; (void)out_size; (void)ws_size;
  const float* x   = (const float*)d_in[0];
  const float* Wq  = (const float*)d_in[1];
  const float* bq  = (const float*)d_in[2];
  const float* Wk  = (const float*)d_in[3];
  const float* bk  = (const float*)d_in[4];
  const float* Wv  = (const float*)d_in[5];
  const float* bv  = (const float*)d_in[6];
  const float* g_q = (const float*)d_in[7];
  const float* b_q = (const float*)d_in[8];
  const float* g_k = (const float*)d_in[9];
  const float* b_k = (const float*)d_in[10];
  const float* Wg  = (const float*)d_in[11];
  const float* bg  = (const float*)d_in[12];
  const float* Wo  = (const float*)d_in[13];
  const float* bo  = (const float*)d_in[14];
  float* out = (float*)d_out;

  const long NE  = 33554432L;   // B*S*E
  const long NE2 = NE / 2;      // 4096*4096
  unsigned short* ws    = (unsigned short*)d_ws;
  unsigned short* xb    = ws;                    // [0, NE)
  unsigned short* Wqkv  = ws + NE;               // [NE, 2.5NE) Wq|Wk|Wv
  unsigned short* qbuf  = ws + NE + 3 * NE2;     // [2.5NE, 3.5NE)
  unsigned short* kbuf  = qbuf + NE;             // [3.5NE, 4.5NE)
  unsigned short* vT    = kbuf + NE;             // [4.5NE, 5.5NE) (B*H,512d,512t)
  unsigned short* Wgb   = Wqkv;                  // 1024x512 (after proj)
  unsigned short* Wob   = Wqkv + 524288;         // 4096x4096 (after proj)
  unsigned short* sbuf  = xb;                    // scores (x dead after proj)
  unsigned short* hbuf  = qbuf;                  // spans qbuf+kbuf (dead after scores)
  unsigned short* wbuf  = xb;                    // scores dead after h-GEMM
  unsigned short* obuf  = kbuf;                  // h dead after gate_norm

  dim3 blk256(256), blk512(512);
  const float isq = 0.044194173824159216f;  // 1/sqrt(512)

  // one merged convert: x | Wq | Wk | Wv  ->  ws[0 .. 2.5NE)
  cvt_multi<<<20480, blk256, 0, stream>>>(x, NE, Wq, NE2, Wk, NE2, Wv, NE2,
                                          ws, (NE + 3 * NE2) / 8);

  // merged q|k|v projection: split-3 epilogue; v written transposed into vT
  gemm256<0, 1, 0, 1><<<1536, blk512, 0, stream>>>(
      xb, Wqkv, bq, bk, bv, qbuf, kbuf, vT,
      4096, 4096, 4096, 4096, 48, 1.f,
      0L, 0L, 1, 0L, 0L, 1, 0L, 0L, 1);

  // Wqkv dead -> convert Wg, Wo into its region (one launch)
  cvt_multi<<<8192, blk256, 0, stream>>>(Wg, 524288L, Wo, NE2,
                                         nullptr, 0L, nullptr, 0L,
                                         Wgb, (524288L + NE2) / 8);

  // layernorm q and k (merged)
  ln_rows2<<<32768, blk256, 0, stream>>>(qbuf, g_q, b_q, kbuf, g_k, b_k, 65536);

  // scores = q @ k^T / sqrt(HD), per (b,h) -> sbuf (=xb)
  gemm256<1, 0, 0, 0><<<dim3(4, 1, 128), blk512, 0, stream>>>(
      qbuf, kbuf, nullptr, nullptr, nullptr, sbuf, nullptr, nullptr,
      512, 4096, 4096, 512, 2, isq,
      2097152L, 512L, 8,
      2097152L, 512L, 8,
      262144L, 0L, 1);

  // h = scores @ Wg^T + bg -> hbuf (=qbuf..kbuf)
  gemm256<1, 0, 0, 1><<<dim3(8, 1, 128), blk512, 0, stream>>>(
      sbuf, Wgb, bg, nullptr, nullptr, hbuf, nullptr, nullptr,
      512, 512, 512, 1024, 4, 1.f,
      262144L, 0L, 1,
      0L, 0L, 1,
      524288L, 0L, 1);

  gate_norm<<<16384, blk256, 0, stream>>>(hbuf, wbuf);

  // attn_out = w @ vT^T -> obuf (=kbuf), (B,S,E) layout
  gemm256<1, 0, 0, 0><<<dim3(4, 1, 128), blk512, 0, stream>>>(
      wbuf, vT, nullptr, nullptr, nullptr, obuf, nullptr, nullptr,
      512, 512, 512, 4096, 2, 1.f,
      262144L, 0L, 1,
      262144L, 0L, 1,
      2097152L, 512L, 8);

  // final = attn_out @ Wo^T + bo -> d_out (f32, nontemporal)
  gemm256<0, 0, 1, 1><<<512, blk512, 0, stream>>>(
      obuf, Wob, bo, nullptr, nullptr, out, nullptr, nullptr,
      4096, 4096, 4096, 4096, 16, 1.f,
      0L, 0L, 1, 0L, 0L, 1, 0L, 0L, 1);
}

// Round 15
// 1208.256 us; speedup vs baseline: 1.0644x; 1.0053x over previous
//
#include <hip/hip_runtime.h>
#include <math.h>

typedef __bf16 bf16x8 __attribute__((ext_vector_type(8)));
typedef float f32x4 __attribute__((ext_vector_type(4)));
typedef short short8 __attribute__((ext_vector_type(8)));
typedef unsigned int uint4v __attribute__((ext_vector_type(4)));

__device__ __forceinline__ float bf2f(unsigned short u) {
  union { unsigned int i; float f; } v; v.i = ((unsigned int)u) << 16; return v.f;
}
__device__ __forceinline__ unsigned short f2bf(float f) {
  union { float fl; unsigned int i; } v; v.fl = f;
  unsigned int x = v.i;
  return (unsigned short)((x + 0x7FFFu + ((x >> 16) & 1u)) >> 16);  // RNE
}
__device__ __forceinline__ unsigned int cvt_pk_bf16(float lo, float hi) {
  unsigned int r;
  asm("v_cvt_pk_bf16_f32 %0, %1, %2" : "=v"(r) : "v"(lo), "v"(hi));
  return r;
}
// async global->LDS, 16B per lane. lds ptr wave-uniform (HW adds lane*16).
__device__ __forceinline__ void gl_lds16(const unsigned short* g, void* l) {
  __builtin_amdgcn_global_load_lds(
      (const __attribute__((address_space(1))) unsigned int*)g,
      (__attribute__((address_space(3))) unsigned int*)l, 16, 0, 0);
}

// ============================================================================
// 256x256 bf16 GEMM, 16x16x32 MFMA. R12/R14-proven configuration (BEST
// measured; unchanged): minimal-barrier drift schedule (2 barriers/tile,
// both pre-MFMA), counted vmcnt(4), 0 K-loop bank conflicts, LDS-transpose
// bf16 epilogue, batched z-major XCD-chunked swizzle, SPLIT3 q|k|vT routing.
// Hazard ledger (per tile t):
//  - Each phase: wave's own lgkmcnt(0) drains its ds_reads before its MFMA
//    AND before it can reach the next barrier.
//  - j1 barrier (pre-MFMA(2)): every wave past it has executed j0's
//    lgkmcnt(0) -> all B(t) frag reads drained before any j2 stageB(t+2)
//    DMA targets B(t)'s slot.
//  - j3 barrier (pre-MFMA(6), after vmcnt): every wave drained through
//    tile t+1's staging loads (FIFO: B(t+1)4 A(t+1)4 | B(t+2)4 -> vmcnt(4))
//    and its own A(t)/B(t) ds_reads -> tile t+1 buffers valid, A(t) slot
//    safe for next j0's stageA(t+2).
// ============================================================================
template<int BATCH, int SPLIT3, int CF32, int HAS_BIAS>
__global__ __launch_bounds__(512)
void gemm256(const unsigned short* __restrict__ A,
             const unsigned short* __restrict__ B,
             const float* __restrict__ b0, const float* __restrict__ b1,
             const float* __restrict__ b2,
             void* __restrict__ C0, void* __restrict__ C1, void* __restrict__ C2,
             int K, int lda, int ldb, int ldc, int nbn, float alpha,
             long sAo, long sAi, int nAi,
             long sBo, long sBi, int nBi,
             long sCo, long sCi, int nCi)
{
  __shared__ alignas(16) unsigned char LDS[131072];
  const int NT = K >> 6;   // even, >= 2

  int tm, tn;
  long offA = 0, offB = 0, offC = 0;
  if (BATCH) {
    // XCD-chunked over z-major flatten (total blocks % 8 == 0):
    // consecutive work-items (same batch) land on the same XCD's L2.
    const int nbx = (int)gridDim.x;
    const int nf = nbx * (int)gridDim.z;
    const int f = (int)blockIdx.z * nbx + (int)blockIdx.x;
    const int s = (f & 7) * (nf >> 3) + (f >> 3);
    const int bx = s % nbx;
    const int z = s / nbx;
    tm = (bx / nbn) * 256;
    tn = (bx % nbn) * 256;
    offA = (long)(z / nAi) * sAo + (long)(z % nAi) * sAi;
    offB = (long)(z / nBi) * sBo + (long)(z % nBi) * sBi;
    offC = (long)(z / nCi) * sCo + (long)(z % nCi) * sCi;
  } else {
    const int nwg = (int)gridDim.x;
    const int bid = (int)blockIdx.x;
    const int s = (bid & 7) * (nwg >> 3) + (bid >> 3);
    const int sTile = s >> 4, w = s & 15;
    const int snb = nbn >> 2;
    tm = ((sTile / snb) * 4 + (w >> 2)) * 256;
    tn = ((sTile % snb) * 4 + (w & 3)) * 256;
  }

  const int tid = (int)threadIdx.x;
  const int lane = tid & 63;
  const int wv = tid >> 6;      // 0..7
  const int wm = wv >> 2;       // 0..1 (A half)
  const int wn = wv & 3;        // 0..3
  const int l16 = lane & 15;
  const int kg = lane >> 4;

  // staging: linear LDS dest; content[o] = logical[o ^ ((row&7)<<4)], row=o>>7
  const int srow = tid >> 3;
  const int scolb = ((tid & 7) * 16) ^ (((tid >> 3) & 7) << 4);
  const unsigned short* Abase = A + offA + (long)tm * lda + (scolb >> 1);
  const unsigned short* Bbase = B + offB + (long)tn * ldb + (scolb >> 1);
  const int ldsw = wv * 1024;

  // frag read cols (full-XOR swizzle on byte col, row&7 == l16&7)
  const int colswz0 = (kg * 16) ^ ((l16 & 7) << 4);
  const int colswz1 = (64 + kg * 16) ^ ((l16 & 7) << 4);

  f32x4 acc[8][4];
  #pragma unroll
  for (int i = 0; i < 8; ++i)
    #pragma unroll
    for (int j = 0; j < 4; ++j)
      #pragma unroll
      for (int e = 0; e < 4; ++e) acc[i][j][e] = 0.f;

  auto stageAh = [&](int t, int h) {       // one A half-tile (2 loads)
    const int buf = t & 1;
    #pragma unroll
    for (int i = 0; i < 2; ++i)
      gl_lds16(Abase + (long)(h * 128 + srow + i * 64) * lda + t * 64,
               &LDS[buf * 32768 + h * 16384 + i * 8192 + ldsw]);
  };
  auto stageBh = [&](int t, int h) {       // one B half-tile (2 loads)
    const int buf = t & 1;
    #pragma unroll
    for (int i = 0; i < 2; ++i)
      gl_lds16(Bbase + (long)(h * 128 + srow + i * 64) * ldb + t * 64,
               &LDS[65536 + buf * 32768 + h * 16384 + i * 8192 + ldsw]);
  };

  // prologue: tiles 0,1 staged (8 loads each); wait tile 0 only
  stageAh(0, 0); stageAh(0, 1); stageBh(0, 0); stageBh(0, 1);
  stageAh(1, 0); stageAh(1, 1); stageBh(1, 0); stageBh(1, 1);
  asm volatile("s_waitcnt vmcnt(8)" ::: "memory");
  __builtin_amdgcn_s_barrier();

  for (int t = 0; t < NT; ++t) {
    const unsigned char* aB = &LDS[(t & 1) * 32768 + wm * 16384];
    const unsigned char* bB = &LDS[65536 + (t & 1) * 32768 + (wn >> 1) * 16384];
    const int brow = (wn & 1) * 64;
    bf16x8 bfrag[4][2];
    #pragma unroll
    for (int j = 0; j < 4; ++j) {
      bf16x8 a0k0 = *(const bf16x8*)(aB + ((2 * j + 0) * 16 + l16) * 128 + colswz0);
      bf16x8 a0k1 = *(const bf16x8*)(aB + ((2 * j + 0) * 16 + l16) * 128 + colswz1);
      bf16x8 a1k0 = *(const bf16x8*)(aB + ((2 * j + 1) * 16 + l16) * 128 + colswz0);
      bf16x8 a1k1 = *(const bf16x8*)(aB + ((2 * j + 1) * 16 + l16) * 128 + colswz1);
      if (j == 0) {
        #pragma unroll
        for (int ni = 0; ni < 4; ++ni) {
          bfrag[ni][0] = *(const bf16x8*)(bB + (brow + ni * 16 + l16) * 128 + colswz0);
          bfrag[ni][1] = *(const bf16x8*)(bB + (brow + ni * 16 + l16) * 128 + colswz1);
        }
        if (t > 0 && t + 1 < NT) stageAh(t + 1, 0);
      } else if (j == 1) {
        if (t > 0 && t + 1 < NT) stageAh(t + 1, 1);
      } else if (j == 2) {
        if (t + 2 < NT) stageBh(t + 2, 0);
      } else {
        if (t + 2 < NT) stageBh(t + 2, 1);
      }
      asm volatile("s_waitcnt lgkmcnt(0)" ::: "memory");
      __builtin_amdgcn_sched_barrier(0);
      if (j == 1) {
        __builtin_amdgcn_s_barrier();          // pre-MFMA: B(t)-slot protection
      } else if (j == 3) {
        if (t >= NT - 2) { asm volatile("s_waitcnt vmcnt(0)" ::: "memory"); }
        else             { asm volatile("s_waitcnt vmcnt(4)" ::: "memory"); }
        __builtin_amdgcn_sched_barrier(0);
        __builtin_amdgcn_s_barrier();          // pre-MFMA: tile boundary
      }
      __builtin_amdgcn_s_setprio(1);
      #pragma unroll
      for (int ni = 0; ni < 4; ++ni) {
        acc[2 * j + 0][ni] = __builtin_amdgcn_mfma_f32_16x16x32_bf16(a0k0, bfrag[ni][0], acc[2 * j + 0][ni], 0, 0, 0);
        acc[2 * j + 0][ni] = __builtin_amdgcn_mfma_f32_16x16x32_bf16(a0k1, bfrag[ni][1], acc[2 * j + 0][ni], 0, 0, 0);
        acc[2 * j + 1][ni] = __builtin_amdgcn_mfma_f32_16x16x32_bf16(a1k0, bfrag[ni][0], acc[2 * j + 1][ni], 0, 0, 0);
        acc[2 * j + 1][ni] = __builtin_amdgcn_mfma_f32_16x16x32_bf16(a1k1, bfrag[ni][1], acc[2 * j + 1][ni], 0, 0, 0);
      }
      __builtin_amdgcn_s_setprio(0);
    }
  }
  // Post-loop: every wave's ds_reads are drained (its own last lgkmcnt(0)),
  // and all waves passed the last tile's pre-MFMA barrier; remaining MFMA
  // work is register-only -> LDS safely reusable per-wave for the epilogue.

  // epilogue: C/D layout col=lane&15, row=(lane>>4)*4 + j (m89-verified)
  const int which = SPLIT3 ? (tn >> 12) : 0;
  const float* bp = SPLIT3 ? (which == 0 ? b0 : (which == 1 ? b1 : b2)) : b0;
  void* Cp = SPLIT3 ? (which == 0 ? C0 : (which == 1 ? C1 : C2)) : C0;
  const int tnn = SPLIT3 ? (tn & 4095) : tn;

  if (CF32) {
    // f32 path (final GEMM): nontemporal direct stores (never re-read)
    #pragma unroll
    for (int ni = 0; ni < 4; ++ni) {
      const int col = tnn + wn * 64 + ni * 16 + l16;
      const float bv = HAS_BIAS ? bp[col] : 0.f;
      #pragma unroll
      for (int mi = 0; mi < 8; ++mi)
        #pragma unroll
        for (int jj = 0; jj < 4; ++jj) {
          const int row = tm + wm * 128 + mi * 16 + kg * 4 + jj;
          __builtin_nontemporal_store(acc[mi][ni][jj] * alpha + bv,
                                      &((float*)Cp)[offC + (long)row * ldc + col]);
        }
    }
  } else if (SPLIT3 && which == 2) {
    // v group: write TRANSPOSED into vT (B*H, 512d, 512t).
    unsigned short* lw = (unsigned short*)&LDS[wv * 16384];
    #pragma unroll
    for (int ni = 0; ni < 4; ++ni) {
      const int dl = ni * 16 + l16;
      const float bv = HAS_BIAS ? bp[tnn + wn * 64 + dl] : 0.f;
      #pragma unroll
      for (int mi = 0; mi < 8; ++mi)
        #pragma unroll
        for (int jj = 0; jj < 4; ++jj) {
          const int tl = mi * 16 + kg * 4 + jj;
          lw[dl * 128 + (tl ^ ((dl & 7) << 4))] = f2bf(acc[mi][ni][jj] * alpha + bv);
        }
    }
    asm volatile("s_waitcnt lgkmcnt(0)" ::: "memory");
    __builtin_amdgcn_sched_barrier(0);
    const int b = tm >> 9, hh = tnn >> 9;
    const int dbase = (tnn & 511) + wn * 64;
    const int tbase = (tm & 511) + wm * 128;
    unsigned short* vTg = (unsigned short*)C2 +
                          ((long)(b * 8 + hh) * 512 + dbase) * 512 + tbase;
    const int dr = lane >> 4, t8 = (lane & 15) * 8;
    #pragma unroll
    for (int i = 0; i < 16; ++i) {
      const int dl = i * 4 + dr;
      short8 val = *(const short8*)&lw[dl * 128 + (t8 ^ ((dl & 7) << 4))];
      __builtin_nontemporal_store(val, (short8*)(vTg + (long)dl * 512 + t8));
    }
  } else {
    // bf16 path: per-wave LDS transpose -> fully coalesced 128B row segments
    unsigned short* lw = (unsigned short*)&LDS[wv * 16384];  // private 16KB
    #pragma unroll
    for (int ni = 0; ni < 4; ++ni) {
      const float bv = HAS_BIAS ? bp[tnn + wn * 64 + ni * 16 + l16] : 0.f;
      #pragma unroll
      for (int mi = 0; mi < 8; ++mi)
        #pragma unroll
        for (int jj = 0; jj < 4; ++jj)
          lw[(mi * 16 + kg * 4 + jj) * 64 + ni * 16 + l16] =
              f2bf(acc[mi][ni][jj] * alpha + bv);
    }
    asm volatile("s_waitcnt lgkmcnt(0)" ::: "memory");
    __builtin_amdgcn_sched_barrier(0);
    unsigned short* Cg = (unsigned short*)Cp + offC +
                         (long)(tm + wm * 128) * ldc + tnn + wn * 64;
    const int rr = lane >> 3, cc = (lane & 7) * 8;
    #pragma unroll
    for (int i = 0; i < 16; ++i) {
      short8 val = *(const short8*)&lw[(i * 8 + rr) * 64 + cc];
      *(short8*)(Cg + (long)(i * 8 + rr) * ldc + cc) = val;
    }
  }
}

// ============================================================================
// merged f32 -> bf16 convert over up to 4 consecutive dst ranges.
// R15: grid capped at 2048 (grid-stride), nontemporal f32 source loads
// (sources never re-read; keeps L2/L3 clean for the bf16 dst the GEMM reads).
// ============================================================================
__global__ __launch_bounds__(256)
void cvt_multi(const float* __restrict__ s0, long n0,
               const float* __restrict__ s1, long n1,
               const float* __restrict__ s2, long n2,
               const float* __restrict__ s3, long n3,
               unsigned short* __restrict__ dst, long n8)
{
  long i = (long)blockIdx.x * 256 + threadIdx.x;
  const long stride = (long)gridDim.x * 256;
  for (; i < n8; i += stride) {
    long e = i * 8;
    const float* src;
    if (e < n0)                    src = s0 + e;
    else if (e < n0 + n1)          src = s1 + (e - n0);
    else if (e < n0 + n1 + n2)     src = s2 + (e - n0 - n1);
    else                           src = s3 + (e - n0 - n1 - n2);
    f32x4 v0 = __builtin_nontemporal_load((const f32x4*)src);
    f32x4 v1 = __builtin_nontemporal_load((const f32x4*)(src + 4));
    uint4v o;
    o[0] = cvt_pk_bf16(v0[0], v0[1]);
    o[1] = cvt_pk_bf16(v0[2], v0[3]);
    o[2] = cvt_pk_bf16(v1[0], v1[1]);
    o[3] = cvt_pk_bf16(v1[2], v1[3]);
    *(uint4v*)(dst + e) = o;
  }
}

// In-place LayerNorm over rows of 512 bf16 for q then k (merged). One wave/row.
__global__ __launch_bounds__(256)
void ln_rows2(unsigned short* __restrict__ q, const float* __restrict__ gq,
              const float* __restrict__ bq_, unsigned short* __restrict__ k,
              const float* __restrict__ gk, const float* __restrict__ bk_,
              int rows_per_tensor)
{
  int row = blockIdx.x * 4 + ((int)threadIdx.x >> 6);
  const int lane = (int)threadIdx.x & 63;
  unsigned short* base = q;
  const float* g = gq;
  const float* b = bq_;
  if (row >= rows_per_tensor) { row -= rows_per_tensor; base = k; g = gk; b = bk_; }
  unsigned short* p = base + (long)row * 512 + lane * 8;
  short8 rv = *(const short8*)p;
  float x[8];
  #pragma unroll
  for (int j = 0; j < 8; ++j) x[j] = bf2f((unsigned short)rv[j]);
  float s = 0.f;
  #pragma unroll
  for (int j = 0; j < 8; ++j) s += x[j];
  #pragma unroll
  for (int off = 32; off > 0; off >>= 1) s += __shfl_xor(s, off, 64);
  float mu = s * (1.f / 512.f);
  float vs = 0.f;
  #pragma unroll
  for (int j = 0; j < 8; ++j) { float d = x[j] - mu; vs += d * d; }
  #pragma unroll
  for (int off = 32; off > 0; off >>= 1) vs += __shfl_xor(vs, off, 64);
  float rs = rsqrtf(vs * (1.f / 512.f) + 1e-5f);
  f32x4 gv0 = *(const f32x4*)(g + lane * 8);
  f32x4 gv1 = *(const f32x4*)(g + lane * 8 + 4);
  f32x4 bv0 = *(const f32x4*)(b + lane * 8);
  f32x4 bv1 = *(const f32x4*)(b + lane * 8 + 4);
  short8 ov;
  #pragma unroll
  for (int j = 0; j < 4; ++j) ov[j] = (short)f2bf((x[j] - mu) * rs * gv0[j] + bv0[j]);
  #pragma unroll
  for (int j = 0; j < 4; ++j) ov[4 + j] = (short)f2bf((x[4 + j] - mu) * rs * gv1[j] + bv1[j]);
  *(short8*)p = ov;
}

// w = (val * gelu_exact(gate)) / max(||.||2, 1e-12); h rows are 1024 (val|gate)
__global__ __launch_bounds__(256)
void gate_norm(const unsigned short* __restrict__ h, unsigned short* __restrict__ w)
{
  const int row = blockIdx.x * 4 + ((int)threadIdx.x >> 6);
  const int lane = (int)threadIdx.x & 63;
  const unsigned short* hp = h + (long)row * 1024 + lane * 8;
  short8 vv = *(const short8*)hp;
  short8 gg = *(const short8*)(hp + 512);
  float wv[8];
  float ssq = 0.f;
  #pragma unroll
  for (int j = 0; j < 8; ++j) {
    float val = bf2f((unsigned short)vv[j]);
    float gt  = bf2f((unsigned short)gg[j]);
    float tt  = val * (0.5f * gt * (1.f + erff(gt * 0.70710678118654752f)));
    wv[j] = tt;
    ssq += tt * tt;
  }
  #pragma unroll
  for (int off = 32; off > 0; off >>= 1) ssq += __shfl_xor(ssq, off, 64);
  float scale = 1.f / fmaxf(sqrtf(ssq), 1e-12f);
  short8 ov;
  #pragma unroll
  for (int j = 0; j < 8; ++j) ov[j] = (short)f2bf(wv[j] * scale);
  *(short8*)(w + (long)row * 512 + lane * 8) = ov;
}

extern "C" void kernel_launch(void* const* d_in, const int* in_sizes, int n_in,
                              void* d_out, int out_size, void* d_ws, size_t ws_size,
                              hipStream_t stream)
{
  (void)in_sizes; (void)n_in; (void)out_size; (void)ws_size;
  const float* x   = (const float*)d_in[0];
  const float* Wq  = (const float*)d_in[1];
  const float* bq  = (const float*)d_in[2];
  const float* Wk  = (const float*)d_in[3];
  const float* bk  = (const float*)d_in[4];
  const float* Wv  = (const float*)d_in[5];
  const float* bv  = (const float*)d_in[6];
  const float* g_q = (const float*)d_in[7];
  const float* b_q = (const float*)d_in[8];
  const float* g_k = (const float*)d_in[9];
  const float* b_k = (const float*)d_in[10];
  const float* Wg  = (const float*)d_in[11];
  const float* bg  = (const float*)d_in[12];
  const float* Wo  = (const float*)d_in[13];
  const float* bo  = (const float*)d_in[14];
  float* out = (float*)d_out;

  const long NE  = 33554432L;   // B*S*E
  const long NE2 = NE / 2;      // 4096*4096
  unsigned short* ws    = (unsigned short*)d_ws;
  unsigned short* xb    = ws;                    // [0, NE)
  unsigned short* Wqkv  = ws + NE;               // [NE, 2.5NE) Wq|Wk|Wv
  unsigned short* qbuf  = ws + NE + 3 * NE2;     // [2.5NE, 3.5NE)
  unsigned short* kbuf  = qbuf + NE;             // [3.5NE, 4.5NE)
  unsigned short* vT    = kbuf + NE;             // [4.5NE, 5.5NE) (B*H,512d,512t)
  unsigned short* Wgb   = Wqkv;                  // 1024x512 (after proj)
  unsigned short* Wob   = Wqkv + 524288;         // 4096x4096 (after proj)
  unsigned short* sbuf  = xb;                    // scores (x dead after proj)
  unsigned short* hbuf  = qbuf;                  // spans qbuf+kbuf (dead after scores)
  unsigned short* wbuf  = xb;                    // scores dead after h-GEMM
  unsigned short* obuf  = kbuf;                  // h dead after gate_norm

  dim3 blk256(256), blk512(512);
  const float isq = 0.044194173824159216f;  // 1/sqrt(512)

  // one merged convert: x | Wq | Wk | Wv  ->  ws[0 .. 2.5NE)  (grid-capped)
  cvt_multi<<<2048, blk256, 0, stream>>>(x, NE, Wq, NE2, Wk, NE2, Wv, NE2,
                                         ws, (NE + 3 * NE2) / 8);

  // merged q|k|v projection: split-3 epilogue; v written transposed into vT
  gemm256<0, 1, 0, 1><<<1536, blk512, 0, stream>>>(
      xb, Wqkv, bq, bk, bv, qbuf, kbuf, vT,
      4096, 4096, 4096, 4096, 48, 1.f,
      0L, 0L, 1, 0L, 0L, 1, 0L, 0L, 1);

  // Wqkv dead -> convert Wg, Wo into its region (one launch, grid-capped)
  cvt_multi<<<2048, blk256, 0, stream>>>(Wg, 524288L, Wo, NE2,
                                         nullptr, 0L, nullptr, 0L,
                                         Wgb, (524288L + NE2) / 8);

  // layernorm q and k (merged)
  ln_rows2<<<32768, blk256, 0, stream>>>(qbuf, g_q, b_q, kbuf, g_k, b_k, 65536);

  // scores = q @ k^T / sqrt(HD), per (b,h) -> sbuf (=xb)
  gemm256<1, 0, 0, 0><<<dim3(4, 1, 128), blk512, 0, stream>>>(
      qbuf, kbuf, nullptr, nullptr, nullptr, sbuf, nullptr, nullptr,
      512, 4096, 4096, 512, 2, isq,
      2097152L, 512L, 8,
      2097152L, 512L, 8,
      262144L, 0L, 1);

  // h = scores @ Wg^T + bg -> hbuf (=qbuf..kbuf)
  gemm256<1, 0, 0, 1><<<dim3(8, 1, 128), blk512, 0, stream>>>(
      sbuf, Wgb, bg, nullptr, nullptr, hbuf, nullptr, nullptr,
      512, 512, 512, 1024, 4, 1.f,
      262144L, 0L, 1,
      0L, 0L, 1,
      524288L, 0L, 1);

  gate_norm<<<16384, blk256, 0, stream>>>(hbuf, wbuf);

  // attn_out = w @ vT^T -> obuf (=kbuf), (B,S,E) layout
  gemm256<1, 0, 0, 0><<<dim3(4, 1, 128), blk512, 0, stream>>>(
      wbuf, vT, nullptr, nullptr, nullptr, obuf, nullptr, nullptr,
      512, 512, 512, 4096, 2, 1.f,
      262144L, 0L, 1,
      262144L, 0L, 1,
      2097152L, 512L, 8);

  // final = attn_out @ Wo^T + bo -> d_out (f32, nontemporal)
  gemm256<0, 0, 1, 1><<<512, blk512, 0, stream>>>(
      obuf, Wob, bo, nullptr, nullptr, out, nullptr, nullptr,
      4096, 4096, 4096, 4096, 16, 1.f,
      0L, 0L, 1, 0L, 0L, 1, 0L, 0L, 1);
}